// Round 1
// baseline (907.714 us; speedup 1.0000x reference)
//
#include <hip/hip_runtime.h>

// GCN 2-layer: out = A_norm * relu(A_norm * (X W1) + b1) * W2 + b2
// A_norm = D^-1/2 (A + I) D^-1/2, D = in-degree incl self-loop (dst-based).
// Strategy: pre-scale rows by dinv, scatter-add raw rows via per-edge wave
// atomics, post-scale by dinv. Self-loop handled by initializing the
// aggregation buffer with the pre-scaled rows (d2d memcpy).

__global__ __launch_bounds__(256) void k_deg_init(float* deg, int n) {
    int i = blockIdx.x * 256 + threadIdx.x;
    if (i < n) deg[i] = 1.0f;  // self-loop
}

__global__ __launch_bounds__(256) void k_deg_count(const int* __restrict__ dst, float* deg, int E) {
    int i = blockIdx.x * 256 + threadIdx.x;
    int stride = gridDim.x * 256;
    for (int e = i; e < E; e += stride) atomicAdd(&deg[dst[e]], 1.0f);
}

// g1[row] = (x[row] @ W1) * rsqrt(deg[row]);  [N,128]@[128,64]
__global__ __launch_bounds__(256) void k_gemm1(const float* __restrict__ x, const float* __restrict__ W1,
                                               const float* __restrict__ deg, float* __restrict__ g1,
                                               int n) {
    __shared__ float Ws[128 * 64];   // 32 KB
    __shared__ float xs[4][128];     // 2 KB
    int tid = threadIdx.x;
    for (int i = tid; i < 128 * 64; i += 256) Ws[i] = W1[i];
    int nrg = n >> 2;                // 25000 row-groups of 4
    int r = tid >> 6, col = tid & 63;  // wave = one row, lanes = 64 cols (2-way LDS alias = free)
    for (int rg = blockIdx.x; rg < nrg; rg += gridDim.x) {
        __syncthreads();
        int row0 = rg << 2;
        for (int i = tid; i < 512; i += 256) xs[i >> 7][i & 127] = x[row0 * 128 + i];
        __syncthreads();
        float acc = 0.f;
#pragma unroll
        for (int k = 0; k < 128; ++k) acc += xs[r][k] * Ws[k * 64 + col];
        int row = row0 + r;
        g1[row * 64 + col] = acc * rsqrtf(deg[row]);
    }
}

// agg[dst] += g[src], one wave per edge, lane = feature
template <int FD>
__global__ __launch_bounds__(256) void k_edge(const int* __restrict__ src, const int* __restrict__ dst,
                                              const float* __restrict__ g, float* __restrict__ agg, int E) {
    int wid = (blockIdx.x * 256 + threadIdx.x) >> 6;
    int lane = threadIdx.x & 63;
    int nw = (gridDim.x * 256) >> 6;
    for (int e = wid; e < E; e += nw) {
        int s = src[e];
        int d = dst[e];
        if (FD == 64 || lane < FD)
            atomicAdd(&agg[d * FD + lane], g[s * FD + lane]);
    }
}

// g2[row] = (relu(agg1[row]*dinv[row] + b1) @ W2) * dinv[row];  [N,64]@[64,40]
__global__ __launch_bounds__(256) void k_gemm2(const float* __restrict__ agg1, const float* __restrict__ W2,
                                               const float* __restrict__ b1, const float* __restrict__ deg,
                                               float* __restrict__ g2, int n) {
    __shared__ float Ws[64 * 40];    // 10 KB
    __shared__ float xs[32][65];     // 8.3 KB, +1 pad breaks 8-way bank conflict
    int tid = threadIdx.x;
    for (int i = tid; i < 64 * 40; i += 256) Ws[i] = W2[i];
    int nrg = n >> 5;                // 3125 row-groups of 32
    int r = tid >> 3, cb = (tid & 7) * 5;  // thread: row r, cols [cb, cb+5)
    for (int rg = blockIdx.x; rg < nrg; rg += gridDim.x) {
        __syncthreads();
        int row0 = rg << 5;
        for (int i = tid; i < 32 * 64; i += 256) {
            int rr = i >> 6, k = i & 63;
            int row = row0 + rr;
            float v = agg1[row * 64 + k] * rsqrtf(deg[row]) + b1[k];
            xs[rr][k] = v > 0.f ? v : 0.f;
        }
        __syncthreads();
        float acc[5] = {0.f, 0.f, 0.f, 0.f, 0.f};
#pragma unroll
        for (int k = 0; k < 64; ++k) {
            float xv = xs[r][k];
#pragma unroll
            for (int j = 0; j < 5; ++j) acc[j] += xv * Ws[k * 40 + cb + j];
        }
        int row = row0 + r;
        float di = rsqrtf(deg[row]);
#pragma unroll
        for (int j = 0; j < 5; ++j) g2[row * 40 + cb + j] = acc[j] * di;
    }
}

// out = out * dinv[row] + b2[col], in place
__global__ __launch_bounds__(256) void k_final(float* __restrict__ out, const float* __restrict__ deg,
                                               const float* __restrict__ b2, int total) {
    int i = blockIdx.x * 256 + threadIdx.x;
    if (i < total) {
        int row = i / 40;
        int c = i - row * 40;
        out[i] = out[i] * rsqrtf(deg[row]) + b2[c];
    }
}

extern "C" void kernel_launch(void* const* d_in, const int* in_sizes, int n_in,
                              void* d_out, int out_size, void* d_ws, size_t ws_size,
                              hipStream_t stream) {
    const float* x  = (const float*)d_in[0];
    const int*   ei = (const int*)d_in[1];
    const float* W1 = (const float*)d_in[2];
    const float* b1 = (const float*)d_in[3];
    const float* W2 = (const float*)d_in[4];
    const float* b2 = (const float*)d_in[5];
    float* out = (float*)d_out;

    int N = in_sizes[0] / 128;   // 100000
    int E = in_sizes[1] / 2;     // 1600000
    const int* src = ei;
    const int* dst = ei + E;

    float* ws   = (float*)d_ws;
    float* deg  = ws;                            // N floats
    float* g1   = ws + ((N + 255) & ~255);       // N*64
    float* agg1 = g1 + (size_t)N * 64;           // N*64
    float* g2   = agg1 + (size_t)N * 64;         // N*40
    // total ~67.7 MB of ws

    k_deg_init<<<(N + 255) / 256, 256, 0, stream>>>(deg, N);
    k_deg_count<<<2048, 256, 0, stream>>>(dst, deg, E);
    k_gemm1<<<1024, 256, 0, stream>>>(x, W1, deg, g1, N);
    hipMemcpyAsync(agg1, g1, (size_t)N * 64 * sizeof(float), hipMemcpyDeviceToDevice, stream);
    k_edge<64><<<4096, 256, 0, stream>>>(src, dst, g1, agg1, E);
    k_gemm2<<<1024, 256, 0, stream>>>(agg1, W2, b1, deg, g2, N);
    hipMemcpyAsync(out, g2, (size_t)N * 40 * sizeof(float), hipMemcpyDeviceToDevice, stream);
    k_edge<40><<<4096, 256, 0, stream>>>(src, dst, g2, out, E);
    k_final<<<(N * 40 + 255) / 256, 256, 0, stream>>>(out, deg, b2, N * 40);
}

// Round 2
// 537.344 us; speedup vs baseline: 1.6893x; 1.6893x over previous
//
#include <hip/hip_runtime.h>

// GCN 2-layer via on-device CSR (counting sort by dst) + gather-aggregation.
// out = A_norm * relu(A_norm * (X W1) + b1) * W2 + b2
// A_norm = D^-1/2 (A+I) D^-1/2. Pre-scale rows by dinv, gather-sum, post-scale.
// Self-loop = accumulator initialized with own (pre-scaled) row.

// ---- degree histogram ----
__global__ __launch_bounds__(256) void k_count(const int* __restrict__ dst, int* __restrict__ cnt, int E) {
    int i = blockIdx.x * 256 + threadIdx.x;
    int stride = gridDim.x * 256;
    for (int e = i; e < E; e += stride) atomicAdd(&cnt[dst[e]], 1);
}

// ---- 3-phase exclusive scan of cnt[n] -> rowptr[n+1], cursor, dinv ----
__global__ __launch_bounds__(256) void k_blockreduce(const int* __restrict__ cnt, int* __restrict__ bsum, int n) {
    __shared__ int s[256];
    int tid = threadIdx.x;
    int i = blockIdx.x * 256 + tid;
    s[tid] = (i < n) ? cnt[i] : 0;
    __syncthreads();
    for (int off = 128; off > 0; off >>= 1) {
        if (tid < off) s[tid] += s[tid + off];
        __syncthreads();
    }
    if (tid == 0) bsum[blockIdx.x] = s[0];
}

__global__ __launch_bounds__(512) void k_scansums(int* __restrict__ bsum, int nb) {
    __shared__ int s[512];
    int tid = threadIdx.x;
    int v = (tid < nb) ? bsum[tid] : 0;
    s[tid] = v;
    __syncthreads();
    for (int off = 1; off < 512; off <<= 1) {
        int add = (tid >= off) ? s[tid - off] : 0;
        __syncthreads();
        s[tid] += add;
        __syncthreads();
    }
    if (tid < nb) bsum[tid] = s[tid] - v;  // exclusive
}

__global__ __launch_bounds__(256) void k_blockscan(const int* __restrict__ cnt, const int* __restrict__ bsum,
                                                   int* __restrict__ rowptr, int* __restrict__ cursor,
                                                   float* __restrict__ dinv, int n, int E) {
    __shared__ int s[256];
    int tid = threadIdx.x;
    int i = blockIdx.x * 256 + tid;
    int v = (i < n) ? cnt[i] : 0;
    s[tid] = v;
    __syncthreads();
    for (int off = 1; off < 256; off <<= 1) {
        int add = (tid >= off) ? s[tid - off] : 0;
        __syncthreads();
        s[tid] += add;
        __syncthreads();
    }
    if (i < n) {
        int ex = bsum[blockIdx.x] + s[tid] - v;
        rowptr[i] = ex;
        cursor[i] = ex;
        dinv[i] = rsqrtf((float)(v + 1));  // +1 self-loop
    }
    if (blockIdx.x == 0 && tid == 0) rowptr[n] = E;
}

// ---- scatter edges into CSR buckets ----
__global__ __launch_bounds__(256) void k_scatter(const int* __restrict__ src, const int* __restrict__ dst,
                                                 int* __restrict__ cursor, int* __restrict__ csr, int E) {
    int i = blockIdx.x * 256 + threadIdx.x;
    int stride = gridDim.x * 256;
    for (int e = i; e < E; e += stride) {
        int pos = atomicAdd(&cursor[dst[e]], 1);
        csr[pos] = src[e];
    }
}

// ---- g1[row] = (x[row] @ W1) * dinv[row];  [N,128]@[128,64] ----
__global__ __launch_bounds__(256) void k_gemm1(const float* __restrict__ x, const float* __restrict__ W1,
                                               const float* __restrict__ dinv, float* __restrict__ g1,
                                               int n) {
    __shared__ float Ws[128 * 64];   // 32 KB
    __shared__ float xs[4][128];
    int tid = threadIdx.x;
    for (int i = tid; i < 128 * 64; i += 256) Ws[i] = W1[i];
    int nrg = n >> 2;
    int r = tid >> 6, col = tid & 63;
    for (int rg = blockIdx.x; rg < nrg; rg += gridDim.x) {
        __syncthreads();
        int row0 = rg << 2;
        for (int i = tid; i < 512; i += 256) xs[i >> 7][i & 127] = x[row0 * 128 + i];
        __syncthreads();
        float acc = 0.f;
#pragma unroll
        for (int k = 0; k < 128; ++k) acc += xs[r][k] * Ws[k * 64 + col];
        int row = row0 + r;
        g1[row * 64 + col] = acc * dinv[row];
    }
}

// ---- layer-1 aggregation: agg1[v] = dinv[v]*(g1[v] + sum_{s in N(v)} g1[s]) ----
// one wave per node; 4 edges in flight (sub = lane>>4), 16 lanes x float4 = 64 feats
__global__ __launch_bounds__(256) void k_agg1(const float* __restrict__ g1, const int* __restrict__ rowptr,
                                              const int* __restrict__ csr, const float* __restrict__ dinv,
                                              float* __restrict__ agg1, int n) {
    int lane = threadIdx.x & 63;
    int v = blockIdx.x * 4 + (threadIdx.x >> 6);
    if (v >= n) return;
    int beg = rowptr[v], end = rowptr[v + 1];
    int sub = lane >> 4, fl = lane & 15;
    float4 acc = {0.f, 0.f, 0.f, 0.f};
    for (int i = beg + sub; i < end; i += 4) {
        int s = csr[i];
        float4 r = *reinterpret_cast<const float4*>(&g1[(size_t)s * 64 + fl * 4]);
        acc.x += r.x; acc.y += r.y; acc.z += r.z; acc.w += r.w;
    }
#pragma unroll
    for (int off = 16; off < 64; off <<= 1) {
        acc.x += __shfl_xor(acc.x, off);
        acc.y += __shfl_xor(acc.y, off);
        acc.z += __shfl_xor(acc.z, off);
        acc.w += __shfl_xor(acc.w, off);
    }
    if (sub == 0) {
        float4 self = *reinterpret_cast<const float4*>(&g1[(size_t)v * 64 + fl * 4]);
        float d = dinv[v];
        float4 o;
        o.x = (acc.x + self.x) * d;
        o.y = (acc.y + self.y) * d;
        o.z = (acc.z + self.z) * d;
        o.w = (acc.w + self.w) * d;
        *reinterpret_cast<float4*>(&agg1[(size_t)v * 64 + fl * 4]) = o;
    }
}

// ---- g2[row] = (relu(agg1[row] + b1) @ W2) * dinv[row];  [N,64]@[64,40] ----
__global__ __launch_bounds__(256) void k_gemm2(const float* __restrict__ agg1, const float* __restrict__ W2,
                                               const float* __restrict__ b1, const float* __restrict__ dinv,
                                               float* __restrict__ g2, int n) {
    __shared__ float Ws[64 * 40];
    __shared__ float xs[32][65];
    int tid = threadIdx.x;
    for (int i = tid; i < 64 * 40; i += 256) Ws[i] = W2[i];
    int nrg = n >> 5;
    int r = tid >> 3, cb = (tid & 7) * 5;
    for (int rg = blockIdx.x; rg < nrg; rg += gridDim.x) {
        __syncthreads();
        int row0 = rg << 5;
        for (int i = tid; i < 32 * 64; i += 256) {
            int rr = i >> 6, k = i & 63;
            float vv = agg1[(row0 + rr) * 64 + k] + b1[k];
            xs[rr][k] = vv > 0.f ? vv : 0.f;
        }
        __syncthreads();
        float acc[5] = {0.f, 0.f, 0.f, 0.f, 0.f};
#pragma unroll
        for (int k = 0; k < 64; ++k) {
            float xv = xs[r][k];
#pragma unroll
            for (int j = 0; j < 5; ++j) acc[j] += xv * Ws[k * 40 + cb + j];
        }
        int row = row0 + r;
        float di = dinv[row];
#pragma unroll
        for (int j = 0; j < 5; ++j) g2[row * 40 + cb + j] = acc[j] * di;
    }
}

// ---- layer-2 aggregation + bias: out[v] = dinv[v]*(g2[v] + sum g2[s]) + b2 ----
// 40 feats: 10 lanes x float4 per edge slot
__global__ __launch_bounds__(256) void k_agg2(const float* __restrict__ g2, const int* __restrict__ rowptr,
                                              const int* __restrict__ csr, const float* __restrict__ dinv,
                                              const float* __restrict__ b2, float* __restrict__ out, int n) {
    int lane = threadIdx.x & 63;
    int v = blockIdx.x * 4 + (threadIdx.x >> 6);
    if (v >= n) return;
    int beg = rowptr[v], end = rowptr[v + 1];
    int sub = lane >> 4, fl = lane & 15;
    float4 acc = {0.f, 0.f, 0.f, 0.f};
    if (fl < 10) {
        for (int i = beg + sub; i < end; i += 4) {
            int s = csr[i];
            float4 r = *reinterpret_cast<const float4*>(&g2[(size_t)s * 40 + fl * 4]);
            acc.x += r.x; acc.y += r.y; acc.z += r.z; acc.w += r.w;
        }
    }
#pragma unroll
    for (int off = 16; off < 64; off <<= 1) {
        acc.x += __shfl_xor(acc.x, off);
        acc.y += __shfl_xor(acc.y, off);
        acc.z += __shfl_xor(acc.z, off);
        acc.w += __shfl_xor(acc.w, off);
    }
    if (sub == 0 && fl < 10) {
        float4 self = *reinterpret_cast<const float4*>(&g2[(size_t)v * 40 + fl * 4]);
        float4 bb = *reinterpret_cast<const float4*>(&b2[fl * 4]);
        float d = dinv[v];
        float4 o;
        o.x = (acc.x + self.x) * d + bb.x;
        o.y = (acc.y + self.y) * d + bb.y;
        o.z = (acc.z + self.z) * d + bb.z;
        o.w = (acc.w + self.w) * d + bb.w;
        *reinterpret_cast<float4*>(&out[(size_t)v * 40 + fl * 4]) = o;
    }
}

extern "C" void kernel_launch(void* const* d_in, const int* in_sizes, int n_in,
                              void* d_out, int out_size, void* d_ws, size_t ws_size,
                              hipStream_t stream) {
    const float* x  = (const float*)d_in[0];
    const int*   ei = (const int*)d_in[1];
    const float* W1 = (const float*)d_in[2];
    const float* b1 = (const float*)d_in[3];
    const float* W2 = (const float*)d_in[4];
    const float* b2 = (const float*)d_in[5];
    float* out = (float*)d_out;

    int N = in_sizes[0] / 128;   // 100000
    int E = in_sizes[1] / 2;     // 1600000
    const int* src = ei;
    const int* dst = ei + E;

    int Np = (N + 255) & ~255;           // padded
    int nblk = (N + 255) / 256;          // 391

    char* w = (char*)d_ws;
    int*   cnt    = (int*)w;                 w += (size_t)Np * 4;
    int*   rowptr = (int*)w;                 w += (size_t)Np * 4 + 256;
    int*   cursor = (int*)w;                 w += (size_t)Np * 4;
    float* dinv   = (float*)w;               w += (size_t)Np * 4;
    int*   bsum   = (int*)w;                 w += 512 * 4;
    int*   csr    = (int*)w;                 w += (size_t)E * 4;
    float* g1     = (float*)w;               w += (size_t)N * 64 * 4;
    float* agg1   = (float*)w;               w += (size_t)N * 64 * 4;
    float* g2     = g1;                      // g1 dead after k_agg1

    hipMemsetAsync(cnt, 0, (size_t)Np * 4, stream);
    k_count<<<2048, 256, 0, stream>>>(dst, cnt, E);
    k_blockreduce<<<nblk, 256, 0, stream>>>(cnt, bsum, N);
    k_scansums<<<1, 512, 0, stream>>>(bsum, nblk);
    k_blockscan<<<nblk, 256, 0, stream>>>(cnt, bsum, rowptr, cursor, dinv, N, E);
    k_scatter<<<2048, 256, 0, stream>>>(src, dst, cursor, csr, E);

    k_gemm1<<<1024, 256, 0, stream>>>(x, W1, dinv, g1, N);
    k_agg1<<<(N + 3) / 4, 256, 0, stream>>>(g1, rowptr, csr, dinv, agg1, N);
    k_gemm2<<<1024, 256, 0, stream>>>(agg1, W2, b1, dinv, g2, N);
    k_agg2<<<(N + 3) / 4, 256, 0, stream>>>(g2, rowptr, csr, dinv, b2, out, N);
}